// Round 12
// baseline (71.271 us; speedup 1.0000x reference)
//
#include <hip/hip_runtime.h>

#define H 1536
#define BD 128
#define ROWS 16
#define NTHREADS 512
#define NBLOCKS 1024   // 16384 rows / 16

using f16x8 = _Float16 __attribute__((ext_vector_type(8)));
using f16x4 = _Float16 __attribute__((ext_vector_type(4)));
using f32x4 = float __attribute__((ext_vector_type(4)));

// ---------------------------------------------------------------------------
// Kernel 0: pack weights fp32 -> fp16 in MFMA fragment order (R2-verified).
//   wdp frag f = w*48+kk: Wd[16w+(l&15)][32*kk+8*(l>>4)+e]
//   wup frag g = w*48+nf*4+kf: Wu[192w+16nf+(l&15)][32*kf+8*(l>>4)+e]
// Used as (swapped) A-operands: every hot-loop weight load = base + lane*16B.
// ---------------------------------------------------------------------------
__global__ __launch_bounds__(256) void pack_weights(const float* __restrict__ wd,
                                                    const float* __restrict__ wu,
                                                    _Float16* __restrict__ wdp,
                                                    _Float16* __restrict__ wup) {
    int f = blockIdx.x * 256 + threadIdx.x;   // 0..49151
    const float* src;
    _Float16* dst;
    if (f < 24576) {
        int w = f / 3072, rem = f - w * 3072;
        int kk = rem >> 6, l = rem & 63;
        int row = 16 * w + (l & 15);
        int col = 32 * kk + 8 * (l >> 4);
        src = wd + (size_t)row * H + col;     // Wd is [128][1536]
        dst = wdp + (size_t)f * 8;
    } else {
        int g = f - 24576;
        int w = g / 3072, rem = g - w * 3072;
        int t = rem >> 6, l = rem & 63;       // t = nf*4 + kf
        int nf = t >> 2, kf = t & 3;
        int row = 192 * w + 16 * nf + (l & 15);
        int col = 32 * kf + 8 * (l >> 4);
        src = wu + (size_t)row * BD + col;    // Wu is [1536][128]
        dst = wup + (size_t)g * 8;
    }
    float4 v0 = reinterpret_cast<const float4*>(src)[0];
    float4 v1 = reinterpret_cast<const float4*>(src)[1];
    f16x8 h;
    h[0] = (_Float16)v0.x; h[1] = (_Float16)v0.y;
    h[2] = (_Float16)v0.z; h[3] = (_Float16)v0.w;
    h[4] = (_Float16)v1.x; h[5] = (_Float16)v1.y;
    h[6] = (_Float16)v1.z; h[7] = (_Float16)v1.w;
    *reinterpret_cast<f16x8*>(dst) = h;
}

// ---------------------------------------------------------------------------
// Fused adapter, all-fp16, single hs read. hs lives in LDS fp16 (hsb) and is
// updated in place to y by GEMM2's packed 8B RMW epilogue; GEMM1 reads its
// B-fragments directly from hsb (no fp8 copy). Stage is K-chunked and
// pipelined into GEMM1 (R11). Swapped-operand MFMAs (R7/R8): D lane&15 = row,
// reg j = col+j -> all epilogues are packed 8B LDS ops.
// ---------------------------------------------------------------------------
__global__ __launch_bounds__(NTHREADS, 4) void fused_adapter(
    const float* __restrict__ hs,
    const _Float16* __restrict__ wdp,
    const _Float16* __restrict__ wup,
    const float* __restrict__ gamma,
    const float* __restrict__ beta,
    float* __restrict__ out)
{
    // 49152 (hsb) + 4096 (tb16) + 1024 (redS/redQ) + 128 (stats) = 54400 B
    __shared__ alignas(16) char smem[54400];
    _Float16* hsb  = reinterpret_cast<_Float16*>(smem);           // [16][1536]
    _Float16* tb16 = reinterpret_cast<_Float16*>(smem + 49152);   // [16][128]
    float* redS    = reinterpret_cast<float*>(smem + 53248);      // [8][16]
    float* redQ    = redS + 128;
    float* statsM  = redQ + 128;                                  // [16]
    float* statsR  = statsM + 16;                                 // [16]

    const int tid  = threadIdx.x;
    const int lane = tid & 63;
    const int w    = tid >> 6;        // wave 0..7
    const int l15  = lane & 15;
    const int lk   = lane >> 4;       // 0..3
    const long row0 = (long)blockIdx.x * ROWS;
    const float* hsblk = hs + row0 * H;

    const _Float16* wp = wdp + ((size_t)w * 48 * 64 + lane) * 8;
    const _Float16* up = wup + ((size_t)w * 48 * 64 + lane) * 8;

    // stage geometry: thread owns row sr, 8 cols at 8*scg + 256*chunk
    const int sr  = tid >> 5;         // 0..15
    const int scg = tid & 31;         // 0..31
    const int swzs = (sr & 7) << 3;   // fp16-element swizzle (16B granule)
    const float* srow = hsblk + (long)sr * H + scg * 8;

    auto store_chunk = [&](int c, float4 va, float4 vb) {
        int col8 = 8 * scg + 256 * c;
        f16x8 hv;
        hv[0] = (_Float16)va.x; hv[1] = (_Float16)va.y;
        hv[2] = (_Float16)va.z; hv[3] = (_Float16)va.w;
        hv[4] = (_Float16)vb.x; hv[5] = (_Float16)vb.y;
        hv[6] = (_Float16)vb.z; hv[7] = (_Float16)vb.w;
        *reinterpret_cast<f16x8*>(&hsb[sr * H + (col8 ^ swzs)]) = hv;
    };

    // ---- Wd prefetch (4-deep rotation) + stage prologue (chunks 0,1)
    f16x8 bq[4];
#pragma unroll
    for (int i = 0; i < 4; ++i) bq[i] = *reinterpret_cast<const f16x8*>(wp + (size_t)i * 512);

    float4 A0, B0, A1, B1;            // two chunk slots (parity)
    A0 = reinterpret_cast<const float4*>(srow)[0];
    B0 = reinterpret_cast<const float4*>(srow)[1];
    A1 = reinterpret_cast<const float4*>(srow + 256)[0];
    B1 = reinterpret_cast<const float4*>(srow + 256)[1];
    store_chunk(0, A0, B0);
    __syncthreads();                  // chunk 0 visible

    // ---- GEMM1 (fp16, swapped) pipelined over 6 chunks of 256 cols:
    // load chunk c+2 || 8 MFMAs on chunk c || store chunk c+1.
    const int aswz = (l15 & 7) << 3;
    f32x4 accv[4] = {{0,0,0,0},{0,0,0,0},{0,0,0,0},{0,0,0,0}};
#pragma unroll
    for (int c = 0; c < 6; ++c) {
        if (c + 2 < 6) {
            const float4* p = reinterpret_cast<const float4*>(srow + 256 * (c + 2));
            if ((c & 1) == 0) { A0 = p[0]; B0 = p[1]; }
            else              { A1 = p[0]; B1 = p[1]; }
        }
#pragma unroll
        for (int i = 0; i < 8; ++i) {            // k-frags p = 8c..8c+7
            int p = 8 * c + i;
            f16x8 bfrag = *reinterpret_cast<const f16x8*>(
                &hsb[l15 * H + ((8 * lk + 32 * p) ^ aswz)]);
            f16x8 afrag = bq[p & 3];
            if (p + 4 < 48) bq[p & 3] = *reinterpret_cast<const f16x8*>(wp + (size_t)(p + 4) * 512);
            accv[p & 3] = __builtin_amdgcn_mfma_f32_16x16x32_f16(afrag, bfrag, accv[p & 3], 0, 0, 0);
        }
        if (c + 1 < 6) {
            if (((c + 1) & 1) == 0) store_chunk(c + 1, A0, B0);
            else                    store_chunk(c + 1, A1, B1);
            __syncthreads();          // chunk c+1 visible
        }
    }

    // ---- t -> tb16: one packed 8B write (D: lane l15 = t-row, reg j = col)
    {
        f32x4 t0 = (accv[0] + accv[1]) + (accv[2] + accv[3]);
        f16x4 tv;
        tv[0] = (_Float16)t0[0]; tv[1] = (_Float16)t0[1];
        tv[2] = (_Float16)t0[2]; tv[3] = (_Float16)t0[3];
        int c0 = 16 * w + 4 * lk;
        *reinterpret_cast<f16x4*>(&tb16[l15 * BD + (c0 ^ aswz)]) = tv;
    }
    __syncthreads();                                // B2: tb16 ready

    // ---- GEMM2 (fp16, swapped) + in-place y RMW + stats
    f16x8 a2f[4];
#pragma unroll
    for (int kf = 0; kf < 4; ++kf)
        a2f[kf] = *reinterpret_cast<const f16x8*>(&tb16[l15 * BD + ((8 * lk + 32 * kf) ^ aswz)]);

    f16x8 uq[4];
#pragma unroll
    for (int i = 0; i < 4; ++i) uq[i] = *reinterpret_cast<const f16x8*>(up + (size_t)i * 512);

    float s = 0.f, q = 0.f;
#pragma unroll
    for (int nf = 0; nf < 12; ++nf) {
        f32x4 acc = {0.f, 0.f, 0.f, 0.f};
#pragma unroll
        for (int kf = 0; kf < 4; ++kf) {
            int g = nf * 4 + kf;
            f16x8 u = uq[g & 3];
            if (g + 4 < 48) uq[g & 3] = *reinterpret_cast<const f16x8*>(up + (size_t)(g + 4) * 512);
            acc = __builtin_amdgcn_mfma_f32_16x16x32_f16(u, a2f[kf], acc, 0, 0, 0);
        }
        int cx = 192 * w + 16 * nf + 4 * lk;
        int idx = l15 * H + (cx ^ aswz);            // 4-aligned, 8B op ok
        f16x4 hv4 = *reinterpret_cast<const f16x4*>(&hsb[idx]);
        float y0 = acc[0] + (float)hv4[0];
        float y1 = acc[1] + (float)hv4[1];
        float y2 = acc[2] + (float)hv4[2];
        float y3 = acc[3] + (float)hv4[3];
        s += (y0 + y1) + (y2 + y3);
        q += (y0 * y0 + y1 * y1) + (y2 * y2 + y3 * y3);
        f16x4 yv;
        yv[0] = (_Float16)y0; yv[1] = (_Float16)y1;
        yv[2] = (_Float16)y2; yv[3] = (_Float16)y3;
        *reinterpret_cast<f16x4*>(&hsb[idx]) = yv;  // y overwrites hs in place
    }

    // ---- stats: thread's (s,q) cover row l15 only; reduce over lk (shfl 16,32)
    // then across 8 waves via LDS.
    s += __shfl_xor(s, 16); s += __shfl_xor(s, 32);
    q += __shfl_xor(q, 16); q += __shfl_xor(q, 32);
    if (lane < 16) {
        redS[w * 16 + lane] = s;
        redQ[w * 16 + lane] = q;
    }
    __syncthreads();                                // B3: partials + y ready
    if (tid < 16) {
        float S = 0.f, Q = 0.f;
#pragma unroll
        for (int ww = 0; ww < 8; ++ww) {
            S += redS[ww * 16 + tid];
            Q += redQ[ww * 16 + tid];
        }
        float mean = S * (1.0f / (float)H);
        float var  = Q * (1.0f / (float)H) - mean * mean;
        statsM[tid] = mean;
        statsR[tid] = rsqrtf(var + 1e-5f);
    }
    __syncthreads();                                // B4: stats ready

    // ---- final: y from hsb (fp16), normalize, coalesced float4 stores
    {
        const int fr  = tid >> 5;
        const int cid = tid & 31;
        const int fswz = (fr & 7) << 3;
        float mean = statsM[fr];
        float rstd = statsR[fr];
        float* orow = out + (row0 + fr) * H;
#pragma unroll
        for (int k = 0; k < 6; ++k) {
            int col = 8 * (cid + 32 * k);
            f16x8 yv = *reinterpret_cast<const f16x8*>(&hsb[fr * H + (col ^ fswz)]);
            const float4* gp = reinterpret_cast<const float4*>(gamma + col);
            const float4* bp = reinterpret_cast<const float4*>(beta + col);
            float4 g0 = gp[0], g1 = gp[1];
            float4 b0 = bp[0], b1 = bp[1];
            float4 o0, o1;
            o0.x = ((float)yv[0] - mean) * rstd * g0.x + b0.x;
            o0.y = ((float)yv[1] - mean) * rstd * g0.y + b0.y;
            o0.z = ((float)yv[2] - mean) * rstd * g0.z + b0.z;
            o0.w = ((float)yv[3] - mean) * rstd * g0.w + b0.w;
            o1.x = ((float)yv[4] - mean) * rstd * g1.x + b1.x;
            o1.y = ((float)yv[5] - mean) * rstd * g1.y + b1.y;
            o1.z = ((float)yv[6] - mean) * rstd * g1.z + b1.z;
            o1.w = ((float)yv[7] - mean) * rstd * g1.w + b1.w;
            float4* op = reinterpret_cast<float4*>(orow + col);
            op[0] = o0;
            op[1] = o1;
        }
    }
}

extern "C" void kernel_launch(void* const* d_in, const int* in_sizes, int n_in,
                              void* d_out, int out_size, void* d_ws, size_t ws_size,
                              hipStream_t stream) {
    const float* hs    = (const float*)d_in[0];
    const float* wd    = (const float*)d_in[1];
    const float* wu    = (const float*)d_in[2];
    const float* gam   = (const float*)d_in[3];
    const float* bet   = (const float*)d_in[4];
    float* out = (float*)d_out;

    _Float16* wdp = (_Float16*)d_ws;
    _Float16* wup = (_Float16*)((char*)d_ws + (size_t)128 * H * sizeof(_Float16));

    pack_weights<<<192, 256, 0, stream>>>(wd, wu, wdp, wup);
    fused_adapter<<<NBLOCKS, NTHREADS, 0, stream>>>(hs, wdp, wup, gam, bet, out);
}

// Round 13
// 55.585 us; speedup vs baseline: 1.2822x; 1.2822x over previous
//
#include <hip/hip_runtime.h>

#define H 1536
#define BD 128
#define ROWS 16
#define NTHREADS 512
#define NBLOCKS 1024   // 16384 rows / 16

using f16x8 = _Float16 __attribute__((ext_vector_type(8)));
using f16x4 = _Float16 __attribute__((ext_vector_type(4)));
using f32x4 = float __attribute__((ext_vector_type(4)));
using i64x2 = long __attribute__((ext_vector_type(2)));

// Weights |w| <= 6e-4 are BELOW e4m3's denormal floor (2^-9) -> pre-scale by
// 2^14. t stored as t*2^7 in fp8; GEMM2 acc = x*2^21; y = acc*2^-21 + hs.
#define WD_SCALE 16384.0f           // 2^14
#define T8_SCALE (1.0f/128.0f)      // acc1(=t*2^14) * 2^-7 = t*2^7
#define X_SCALE  (1.0f/2097152.0f)  // 2^-21

// ---------------------------------------------------------------------------
// Kernel 0: pack weights fp32 -> fp8(e4m3, x2^14), pair-interleaved fragment
// order (R5-verified, unchanged).
// ---------------------------------------------------------------------------
__global__ __launch_bounds__(256) void pack_weights(const float* __restrict__ wd,
                                                    const float* __restrict__ wu,
                                                    char* __restrict__ wdp8,
                                                    char* __restrict__ wup8) {
    int f = blockIdx.x * 256 + threadIdx.x;   // 0..49151
    const float* src;
    char* dst;
    if (f < 24576) {
        int w = f / 3072, rem = f - w * 3072;
        int ph = rem >> 6, l = rem & 63;      // ph = frag index 0..47
        int row = 16 * w + (l & 15);
        int col = 32 * ph + 8 * (l >> 4);
        src = wd + (size_t)row * H + col;     // Wd is [128][1536]
        int p = ph >> 1, half = ph & 1;
        dst = wdp8 + (((size_t)(w * 24 + p) * 64 + l) * 16 + half * 8);
    } else {
        int g = f - 24576;
        int w = g / 3072, rem = g - w * 3072;
        int t2 = rem >> 6, l = rem & 63;      // t2 = nf*4 + kf
        int nf = t2 >> 2, kf = t2 & 3;
        int row = 192 * w + 16 * nf + (l & 15);
        int col = 32 * kf + 8 * (l >> 4);
        src = wu + (size_t)row * BD + col;    // Wu is [1536][128]
        int q = nf * 2 + (kf >> 1), half = kf & 1;
        dst = wup8 + (((size_t)(w * 24 + q) * 64 + l) * 16 + half * 8);
    }
    float4 v0 = reinterpret_cast<const float4*>(src)[0];
    float4 v1 = reinterpret_cast<const float4*>(src)[1];
    int i0 = __builtin_amdgcn_cvt_pk_fp8_f32(v0.x * WD_SCALE, v0.y * WD_SCALE, 0, false);
    i0     = __builtin_amdgcn_cvt_pk_fp8_f32(v0.z * WD_SCALE, v0.w * WD_SCALE, i0, true);
    int i1 = __builtin_amdgcn_cvt_pk_fp8_f32(v1.x * WD_SCALE, v1.y * WD_SCALE, 0, false);
    i1     = __builtin_amdgcn_cvt_pk_fp8_f32(v1.z * WD_SCALE, v1.w * WD_SCALE, i1, true);
    int2 st = {i0, i1};
    *reinterpret_cast<int2*>(dst) = st;
}

// ---------------------------------------------------------------------------
// Fused adapter = R5 (fp8 GEMMs, fp16 hsb resident, hs read ONCE)
//               + R11 (chunked stage pipelined into GEMM1)
//               + R8 (swapped-operand MFMAs -> packed epilogues).
// GEMM2 epilogue RMWs y = x + hs into hsb in place (8B fp16 ops) and carries
// stats in registers; final normalizes straight from hsb. 9 barriers.
// ---------------------------------------------------------------------------
__global__ __launch_bounds__(NTHREADS, 4) void fused_adapter(
    const float* __restrict__ hs,
    const char* __restrict__ wdp8,
    const char* __restrict__ wup8,
    const float* __restrict__ gamma,
    const float* __restrict__ beta,
    float* __restrict__ out)
{
    // 49152 hsb + 24576 hsa8 + 2048 tb8 + 1152 reductions = 76928 (2 blk/CU)
    __shared__ alignas(16) char smem[76928];
    _Float16* hsb = reinterpret_cast<_Float16*>(smem);            // [16][1536]
    char* hsa8    = smem + 49152;     // [48 frag][64 lane][8B] fp8 copy
    char* tb8     = smem + 73728;     // [4 frag][64][8B]
    float* redS   = reinterpret_cast<float*>(smem + 75776);       // [8][16]
    float* redQ   = redS + 128;
    float* statsM = redQ + 128;                                   // [16]
    float* statsR = statsM + 16;                                  // [16]

    const int tid  = threadIdx.x;
    const int lane = tid & 63;
    const int w    = tid >> 6;        // wave 0..7
    const int l15  = lane & 15;
    const int lk   = lane >> 4;       // 0..3
    const long row0 = (long)blockIdx.x * ROWS;
    const float* hsblk = hs + row0 * H;

    const i64x2* wp2 = reinterpret_cast<const i64x2*>(wdp8) + (size_t)w * 24 * 64 + lane;
    const i64x2* up2 = reinterpret_cast<const i64x2*>(wup8) + (size_t)w * 24 * 64 + lane;

    // stage geometry: thread owns row sr, 8 cols at 8*scg + 256*chunk
    const int sr  = tid >> 5;         // 0..15
    const int scg = tid & 31;         // 0..31
    const int swzs = (sr & 7) << 3;   // hsb swizzle (fp16 elems, 16B granule)
    const float* srow = hsblk + (long)sr * H + scg * 8;

    // store one chunk: fp16 -> hsb (residual) AND fp8 -> hsa8 (GEMM1 frags)
    auto store_chunk = [&](int c, float4 va, float4 vb) {
        int col8 = 8 * scg + 256 * c;
        f16x8 hv;
        hv[0] = (_Float16)va.x; hv[1] = (_Float16)va.y;
        hv[2] = (_Float16)va.z; hv[3] = (_Float16)va.w;
        hv[4] = (_Float16)vb.x; hv[5] = (_Float16)vb.y;
        hv[6] = (_Float16)vb.z; hv[7] = (_Float16)vb.w;
        *reinterpret_cast<f16x8*>(&hsb[sr * H + (col8 ^ swzs)]) = hv;
        int c8 = scg + 32 * c;                    // 8-col group 0..191
        int kk = c8 >> 2, m = c8 & 3;
        int al = (16 * m + sr) ^ ((kk & 15) << 1);
        int j0 = __builtin_amdgcn_cvt_pk_fp8_f32(va.x, va.y, 0, false);
        j0     = __builtin_amdgcn_cvt_pk_fp8_f32(va.z, va.w, j0, true);
        int j1 = __builtin_amdgcn_cvt_pk_fp8_f32(vb.x, vb.y, 0, false);
        j1     = __builtin_amdgcn_cvt_pk_fp8_f32(vb.z, vb.w, j1, true);
        int2 stv = {j0, j1};
        *reinterpret_cast<int2*>(&hsa8[(kk * 64 + al) * 8]) = stv;
    };

    // ---- Wd prefetch (4-deep rotation) + stage prologue (chunks 0,1)
    i64x2 bq[4];
#pragma unroll
    for (int i = 0; i < 4; ++i) bq[i] = wp2[i * 64];

    float4 A0, B0, A1, B1;            // two chunk slots (parity)
    A0 = reinterpret_cast<const float4*>(srow)[0];
    B0 = reinterpret_cast<const float4*>(srow)[1];
    A1 = reinterpret_cast<const float4*>(srow + 256)[0];
    B1 = reinterpret_cast<const float4*>(srow + 256)[1];
    store_chunk(0, A0, B0);
    __syncthreads();                  // chunk 0 visible

    // ---- GEMM1 (fp8, swapped) pipelined over 6 chunks of 256 cols:
    // load chunk c+2 || 4 pair-MFMAs on chunk c || store chunk c+1.
    f32x4 accv[4] = {{0,0,0,0},{0,0,0,0},{0,0,0,0},{0,0,0,0}};
#pragma unroll
    for (int c = 0; c < 6; ++c) {
        if (c + 2 < 6) {
            const float4* p = reinterpret_cast<const float4*>(srow + 256 * (c + 2));
            if ((c & 1) == 0) { A0 = p[0]; B0 = p[1]; }
            else              { A1 = p[0]; B1 = p[1]; }
        }
#pragma unroll
        for (int i = 0; i < 4; ++i) { // pairs p = 4c..4c+3 (k-frags 8c..8c+7)
            int p = 4 * c + i;
            int kk0 = 2 * p, kk1 = 2 * p + 1;
            long blo = *reinterpret_cast<const long*>(&hsa8[(kk0 * 64 + (lane ^ ((kk0 & 15) << 1))) * 8]);
            long bhi = *reinterpret_cast<const long*>(&hsa8[(kk1 * 64 + (lane ^ ((kk1 & 15) << 1))) * 8]);
            i64x2 b = bq[p & 3];
            if (p + 4 < 24) bq[p & 3] = wp2[(p + 4) * 64];
            f32x4 a = accv[p & 3];
            a = __builtin_amdgcn_mfma_f32_16x16x32_fp8_fp8(b[0], blo, a, 0, 0, 0);
            a = __builtin_amdgcn_mfma_f32_16x16x32_fp8_fp8(b[1], bhi, a, 0, 0, 0);
            accv[p & 3] = a;
        }
        if (c + 1 < 6) {
            if (((c + 1) & 1) == 0) store_chunk(c + 1, A0, B0);
            else                    store_chunk(c + 1, A1, B1);
            __syncthreads();          // chunk c+1 visible
        }
    }

    // ---- Wu prefetch (covers tb8 round-trip + barrier)
    i64x2 uq[4];
#pragma unroll
    for (int i = 0; i < 4; ++i) uq[i] = up2[i * 64];

    // ---- t -> tb8: ONE packed ds_write_b32 (swapped D layout, R8-verified)
    {
        f32x4 t0 = (accv[0] + accv[1]) + (accv[2] + accv[3]);
        int p0 = __builtin_amdgcn_cvt_pk_fp8_f32(t0[0] * T8_SCALE, t0[1] * T8_SCALE, 0, false);
        int p1 = __builtin_amdgcn_cvt_pk_fp8_f32(t0[2] * T8_SCALE, t0[3] * T8_SCALE, 0, false);
        unsigned word = (unsigned)(p0 & 0xFFFF) | ((unsigned)(p1 & 0xFFFF) << 16);
        int c0 = 16 * w + 4 * lk;
        int kf = c0 >> 5, hi = (c0 >> 3) & 3, off = c0 & 7;
        *reinterpret_cast<unsigned*>(&tb8[(kf * 64 + hi * 16 + l15) * 8 + off]) = word;
    }
    __syncthreads();                                // B2: tb8 ready

    long a2f8[4];
#pragma unroll
    for (int kf = 0; kf < 4; ++kf)
        a2f8[kf] = *reinterpret_cast<const long*>(&tb8[(kf * 64 + lane) * 8]);

    // ---- GEMM2 (fp8, swapped) + in-place y RMW on hsb + register stats.
    // D: lane l15 = x-row, reg j = x-col cx+j. Wave w owns cols 192w..192w+191.
    float s = 0.f, q = 0.f;
#pragma unroll
    for (int nf = 0; nf < 12; ++nf) {
        i64x2 u0 = uq[(2 * nf) & 3];
        i64x2 u1 = uq[(2 * nf + 1) & 3];
        if (2 * nf + 4 < 24) uq[(2 * nf) & 3]     = up2[(2 * nf + 4) * 64];
        if (2 * nf + 5 < 24) uq[(2 * nf + 1) & 3] = up2[(2 * nf + 5) * 64];
        f32x4 acc = {0.f, 0.f, 0.f, 0.f};
        acc = __builtin_amdgcn_mfma_f32_16x16x32_fp8_fp8(u0[0], a2f8[0], acc, 0, 0, 0);
        acc = __builtin_amdgcn_mfma_f32_16x16x32_fp8_fp8(u0[1], a2f8[1], acc, 0, 0, 0);
        acc = __builtin_amdgcn_mfma_f32_16x16x32_fp8_fp8(u1[0], a2f8[2], acc, 0, 0, 0);
        acc = __builtin_amdgcn_mfma_f32_16x16x32_fp8_fp8(u1[1], a2f8[3], acc, 0, 0, 0);
        int cx = 192 * w + 16 * nf + 4 * lk;
        int idx = l15 * H + (cx ^ ((l15 & 7) << 3));   // 4-aligned, 8B op
        f16x4 hv4 = *reinterpret_cast<const f16x4*>(&hsb[idx]);
        float y0 = acc[0] * X_SCALE + (float)hv4[0];
        float y1 = acc[1] * X_SCALE + (float)hv4[1];
        float y2 = acc[2] * X_SCALE + (float)hv4[2];
        float y3 = acc[3] * X_SCALE + (float)hv4[3];
        s += (y0 + y1) + (y2 + y3);
        q += (y0 * y0 + y1 * y1) + (y2 * y2 + y3 * y3);
        f16x4 yv;
        yv[0] = (_Float16)y0; yv[1] = (_Float16)y1;
        yv[2] = (_Float16)y2; yv[3] = (_Float16)y3;
        *reinterpret_cast<f16x4*>(&hsb[idx]) = yv;     // y overwrites hs
    }

    // ---- stats: (s,q) cover row l15; reduce over lk via shfl, then 8 waves
    s += __shfl_xor(s, 16); s += __shfl_xor(s, 32);
    q += __shfl_xor(q, 16); q += __shfl_xor(q, 32);
    if (lane < 16) {
        redS[w * 16 + lane] = s;
        redQ[w * 16 + lane] = q;
    }
    __syncthreads();                                // B3: partials + y ready
    if (tid < 16) {
        float S = 0.f, Q = 0.f;
#pragma unroll
        for (int ww = 0; ww < 8; ++ww) {
            S += redS[ww * 16 + tid];
            Q += redQ[ww * 16 + tid];
        }
        float mean = S * (1.0f / (float)H);
        float var  = Q * (1.0f / (float)H) - mean * mean;
        statsM[tid] = mean;
        statsR[tid] = rsqrtf(var + 1e-5f);
    }
    __syncthreads();                                // B4: stats ready

    // ---- final: y from hsb (fp16), normalize, coalesced float4 stores
    {
        const int fr  = tid >> 5;
        const int cid = tid & 31;
        const int fswz = (fr & 7) << 3;
        float mean = statsM[fr];
        float rstd = statsR[fr];
        float* orow = out + (row0 + fr) * H;
#pragma unroll
        for (int k = 0; k < 6; ++k) {
            int col = 8 * (cid + 32 * k);
            f16x8 yv = *reinterpret_cast<const f16x8*>(&hsb[fr * H + (col ^ fswz)]);
            const float4* gp = reinterpret_cast<const float4*>(gamma + col);
            const float4* bp = reinterpret_cast<const float4*>(beta + col);
            float4 g0 = gp[0], g1 = gp[1];
            float4 b0 = bp[0], b1 = bp[1];
            float4 o0, o1;
            o0.x = ((float)yv[0] - mean) * rstd * g0.x + b0.x;
            o0.y = ((float)yv[1] - mean) * rstd * g0.y + b0.y;
            o0.z = ((float)yv[2] - mean) * rstd * g0.z + b0.z;
            o0.w = ((float)yv[3] - mean) * rstd * g0.w + b0.w;
            o1.x = ((float)yv[4] - mean) * rstd * g1.x + b1.x;
            o1.y = ((float)yv[5] - mean) * rstd * g1.y + b1.y;
            o1.z = ((float)yv[6] - mean) * rstd * g1.z + b1.z;
            o1.w = ((float)yv[7] - mean) * rstd * g1.w + b1.w;
            float4* op = reinterpret_cast<float4*>(orow + col);
            op[0] = o0;
            op[1] = o1;
        }
    }
}

extern "C" void kernel_launch(void* const* d_in, const int* in_sizes, int n_in,
                              void* d_out, int out_size, void* d_ws, size_t ws_size,
                              hipStream_t stream) {
    const float* hs    = (const float*)d_in[0];
    const float* wd    = (const float*)d_in[1];
    const float* wu    = (const float*)d_in[2];
    const float* gam   = (const float*)d_in[3];
    const float* bet   = (const float*)d_in[4];
    float* out = (float*)d_out;

    char* wdp8 = (char*)d_ws;
    char* wup8 = (char*)d_ws + (size_t)128 * H;   // 196608 B each

    pack_weights<<<192, 256, 0, stream>>>(wd, wu, wdp8, wup8);
    fused_adapter<<<NBLOCKS, NTHREADS, 0, stream>>>(hs, wdp8, wup8, gam, bet, out);
}